// Round 1
// baseline (160.965 us; speedup 1.0000x reference)
//
#include <hip/hip_runtime.h>
#include <stdint.h>

#define B_IMG  8
#define NANCH  17328          // A*HW = 3*5776
#define NCLS   80
#define TOPK   200
#define SORT_N 1024
#define NTHR   256

// ---------------------------------------------------------------------------
// K1: transpose scores [B][N][C] -> [B][C][N] so per-class reads are coalesced
// ---------------------------------------------------------------------------
__global__ __launch_bounds__(NTHR) void transpose_scores_k(
    const float* __restrict__ scores, float* __restrict__ ts) {
  __shared__ float tile[64][81];  // +1 pad: conflict-free transposed reads
  const int b = blockIdx.y;
  const int n0 = blockIdx.x * 64;
  const int tid = threadIdx.x;

  for (int f = tid; f < 64 * NCLS; f += NTHR) {
    int dn = f / NCLS, c = f - dn * NCLS;
    int n = n0 + dn;
    if (n < NANCH) tile[dn][c] = scores[((size_t)b * NANCH + n) * NCLS + c];
  }
  __syncthreads();
  for (int f = tid; f < NCLS * 64; f += NTHR) {
    int c = f >> 6, dn = f & 63;
    int n = n0 + dn;
    if (n < NANCH) ts[((size_t)b * NCLS + c) * NANCH + n] = tile[dn][c];
  }
}

// ---------------------------------------------------------------------------
// K2: per-(image,class) top-200 (exact JAX top_k order) + sequential NMS
// ---------------------------------------------------------------------------
__global__ __launch_bounds__(NTHR) void select_nms_k(
    const float* __restrict__ boxes, const float* __restrict__ scores,
    const float* __restrict__ ts, int use_t, float* __restrict__ out) {
  const int blk = blockIdx.x;
  const int b = blk / NCLS;
  const int c = blk - b * NCLS;
  const int tid = threadIdx.x;

  __shared__ unsigned int hist[256];
  __shared__ unsigned long long keys[SORT_N];
  __shared__ float sx1[TOPK], sy1[TOPK], sx2[TOPK], sy2[TOPK], sar[TOPK], ssc[TOPK];
  __shared__ int skeep[TOPK];
  __shared__ unsigned int sh_cutbits;
  __shared__ int sh_m;

  const float* src;
  int stride;
  if (use_t) { src = ts + ((size_t)b * NCLS + c) * NANCH; stride = 1; }
  else       { src = scores + (size_t)b * NANCH * NCLS + c; stride = NCLS; }

  // ---- pass 1: histogram of score high bits (candidates are in (0.5, 1)) ----
  for (int j = tid; j < 256; j += NTHR) hist[j] = 0;
  if (tid == 0) sh_m = 0;
  __syncthreads();

  for (int i = tid; i < NANCH; i += NTHR) {
    float s = src[(size_t)i * stride];
    if (s > 0.5f) {
      unsigned int fb = __float_as_uint(s);
      unsigned int bin = (fb - 0x3F000000u) >> 15;  // exponent fixed for (0.5,1)
      if (bin > 255u) bin = 255u;
      atomicAdd(&hist[bin], 1u);
    }
  }
  __syncthreads();

  // ---- find cutoff bin: smallest-score bin such that >=200 items above it ----
  if (tid == 0) {
    unsigned int acc = 0;
    int cut = 0;
    for (int bin = 255; bin >= 0; --bin) {
      acc += hist[bin];
      if (acc >= TOPK) { cut = bin; break; }
    }
    sh_cutbits = 0x3F000000u + ((unsigned int)cut << 15);
  }
  __syncthreads();
  const unsigned int cutbits = sh_cutbits;

  // ---- pass 2: compact candidate keys -----------------------------------
  // key = (score_bits << 32) | (~idx)  -> descending order == JAX top_k order
  for (int i = tid; i < NANCH; i += NTHR) {
    float s = src[(size_t)i * stride];
    if (s > 0.5f && __float_as_uint(s) >= cutbits) {
      int slot = atomicAdd(&sh_m, 1);
      if (slot < SORT_N)
        keys[slot] = ((unsigned long long)__float_as_uint(s) << 32) |
                     (unsigned long long)(0xFFFFFFFFu - (unsigned int)i);
    }
  }
  __syncthreads();
  int M = sh_m; if (M > SORT_N) M = SORT_N;
  for (int j = M + tid; j < SORT_N; j += NTHR) keys[j] = 0ull;

  // ---- bitonic sort, descending ------------------------------------------
  for (int size = 2; size <= SORT_N; size <<= 1) {
    for (int st = size >> 1; st > 0; st >>= 1) {
      __syncthreads();
      for (int t = tid; t < SORT_N / 2; t += NTHR) {
        int lo = 2 * t - (t & (st - 1));
        int hi = lo + st;
        bool desc = ((lo & size) == 0);
        unsigned long long a = keys[lo], bb = keys[hi];
        if ((a < bb) == desc) { keys[lo] = bb; keys[hi] = a; }
      }
    }
  }
  __syncthreads();

  // ---- gather top-200 boxes ----------------------------------------------
  if (tid < TOPK) {
    unsigned long long key = keys[tid];
    int valid = (key != 0ull);
    float sc = __uint_as_float((unsigned int)(key >> 32));
    unsigned int idx = 0xFFFFFFFFu - (unsigned int)(key & 0xFFFFFFFFull);
    float4 bx = make_float4(0.f, 0.f, 0.f, 0.f);
    if (valid) bx = ((const float4*)boxes)[(size_t)b * NANCH + idx];
    sx1[tid] = bx.x; sy1[tid] = bx.y; sx2[tid] = bx.z; sy2[tid] = bx.w;
    sar[tid] = __fmul_rn(bx.z - bx.x, bx.w - bx.y);   // _rn: block FMA contraction
    ssc[tid] = valid ? sc : 0.f;
    skeep[tid] = valid;
  }
  __syncthreads();

  // ---- sequential NMS, single wave, register-resident (no barriers) ------
  if (tid < 64) {
    const int lane = tid;
    float x1v[4], y1v[4], x2v[4], y2v[4], av[4];
    int km = 0;  // keep bits for slots j = lane + 64*r
#pragma unroll
    for (int r = 0; r < 4; ++r) {
      int j = lane + (r << 6);
      if (j < TOPK) {
        x1v[r] = sx1[j]; y1v[r] = sy1[j]; x2v[r] = sx2[j]; y2v[r] = sy2[j];
        av[r] = sar[j];
        if (skeep[j]) km |= (1 << r);
      } else {
        x1v[r] = 0.f; y1v[r] = 0.f; x2v[r] = 0.f; y2v[r] = 0.f; av[r] = 0.f;
      }
    }
#pragma unroll
    for (int ri = 0; ri < 4; ++ri) {          // static ri -> register indices
      const int imax = (ri == 3) ? (TOPK - 192) : 64;
      for (int li = 0; li < imax; ++li) {
        const int i = (ri << 6) + li;
        int kmi = __shfl(km, li, 64);         // current keep[i] (wave-uniform)
        if (!((kmi >> ri) & 1)) continue;
        float xi1 = __shfl(x1v[ri], li, 64);
        float yi1 = __shfl(y1v[ri], li, 64);
        float xi2 = __shfl(x2v[ri], li, 64);
        float yi2 = __shfl(y2v[ri], li, 64);
        float ai  = __shfl(av[ri],  li, 64);
#pragma unroll
        for (int r = 0; r < 4; ++r) {
          int j = lane + (r << 6);
          if (j > i && j < TOPK && ((km >> r) & 1)) {
            float xx1 = fmaxf(xi1, x1v[r]);
            float yy1 = fmaxf(yi1, y1v[r]);
            float xx2 = fminf(xi2, x2v[r]);
            float yy2 = fminf(yi2, y2v[r]);
            float iw = fmaxf(0.f, __fsub_rn(xx2, xx1));
            float ih = fmaxf(0.f, __fsub_rn(yy2, yy1));
            float inter = __fmul_rn(iw, ih);
            float denom = __fsub_rn(__fadd_rn(ai, av[r]), inter);
            float iou = __fdiv_rn(inter, denom);   // IEEE div: matches XLA bitwise
            if (iou > 0.5f) km &= ~(1 << r);
          }
        }
      }
    }
#pragma unroll
    for (int r = 0; r < 4; ++r) {
      int j = lane + (r << 6);
      if (j < TOPK) skeep[j] = (km >> r) & 1;
    }
  }
  __syncthreads();

  // ---- emit (box4, score, class) rows, zeroed where not kept -------------
  const size_t base = ((size_t)b * NCLS + c) * (TOPK * 6);
  for (int f = tid; f < TOPK * 6; f += NTHR) {
    int k = f / 6, comp = f - k * 6;
    float v = 0.f;
    if (skeep[k]) {
      switch (comp) {
        case 0: v = sx1[k]; break;
        case 1: v = sy1[k]; break;
        case 2: v = sx2[k]; break;
        case 3: v = sy2[k]; break;
        case 4: v = ssc[k]; break;
        default: v = (float)c; break;
      }
    }
    out[base + f] = v;
  }
}

// ---------------------------------------------------------------------------
extern "C" void kernel_launch(void* const* d_in, const int* in_sizes, int n_in,
                              void* d_out, int out_size, void* d_ws, size_t ws_size,
                              hipStream_t stream) {
  (void)in_sizes; (void)n_in; (void)out_size;
  const float* boxes  = (const float*)d_in[0];
  const float* scores = (const float*)d_in[1];
  float* out = (float*)d_out;

  const size_t need = (size_t)B_IMG * NCLS * NANCH * sizeof(float);  // 44.4 MB
  int use_t = (ws_size >= need) ? 1 : 0;
  float* ts = (float*)d_ws;

  if (use_t) {
    dim3 grid((NANCH + 63) / 64, B_IMG);
    transpose_scores_k<<<grid, NTHR, 0, stream>>>(scores, ts);
  }
  select_nms_k<<<B_IMG * NCLS, NTHR, 0, stream>>>(boxes, scores, ts, use_t, out);
}

// Round 2
// 129.477 us; speedup vs baseline: 1.2432x; 1.2432x over previous
//
#include <hip/hip_runtime.h>
#include <stdint.h>

#define B_IMG  8
#define NANCH  17328          // A*HW = 3*5776
#define NCLS   80
#define TOPK   200
#define NPART  4
#define PARTN  (NANCH / NPART)    // 4332
#define PARTN4 (PARTN / 4)        // 1083 float4s
#define NTHR   256

// ---------------------------------------------------------------------------
// K1: transpose scores [B][N][C] -> [B][C][N] so per-class reads are coalesced
// ---------------------------------------------------------------------------
__global__ __launch_bounds__(NTHR) void transpose_scores_k(
    const float* __restrict__ scores, float* __restrict__ ts) {
  __shared__ float tile[64][81];  // +1 pad: conflict-free transposed reads
  const int b = blockIdx.y;
  const int n0 = blockIdx.x * 64;
  const int tid = threadIdx.x;

  for (int f = tid; f < 64 * NCLS; f += NTHR) {
    int dn = f / NCLS, c = f - dn * NCLS;
    int n = n0 + dn;
    if (n < NANCH) tile[dn][c] = scores[((size_t)b * NANCH + n) * NCLS + c];
  }
  __syncthreads();
  for (int f = tid; f < NCLS * 64; f += NTHR) {
    int c = f >> 6, dn = f & 63;
    int n = n0 + dn;
    if (n < NANCH) ts[((size_t)b * NCLS + c) * NANCH + n] = tile[dn][c];
  }
}

// ---------------------------------------------------------------------------
// helpers
// ---------------------------------------------------------------------------
__device__ __forceinline__ void hist_add(float s, unsigned int* hist) {
  if (s > 0.5f) {
    unsigned int bin = (__float_as_uint(s) - 0x3F000000u) >> 15;
    if (bin > 255u) bin = 255u;
    atomicAdd(&hist[bin], 1u);
  }
}

__device__ __forceinline__ void compact_add(float s, int gidx, unsigned int cutbits,
                                            unsigned long long* keys, int* sh_m) {
  if (s > 0.5f && __float_as_uint(s) >= cutbits) {
    int slot = atomicAdd(sh_m, 1);
    if (slot < 512)
      keys[slot] = ((unsigned long long)__float_as_uint(s) << 32) |
                   (unsigned long long)(0xFFFFFFFFu - (unsigned int)gidx);
  }
}

// ---------------------------------------------------------------------------
// K2 (stage 1): per-(b,c,part) exact top-200 keys -> global ws
// blk = (b*NCLS + c)*NPART + p
// ---------------------------------------------------------------------------
__global__ __launch_bounds__(NTHR) void stage1_k(
    const float* __restrict__ scores, const float* __restrict__ ts, int use_t,
    unsigned long long* __restrict__ topkeys) {
  const int blk = blockIdx.x;
  const int p = blk & (NPART - 1);
  const int bc = blk >> 2;
  const int b = bc / NCLS;
  const int c = bc - b * NCLS;
  const int tid = threadIdx.x;

  __shared__ unsigned int hist[256];
  __shared__ unsigned long long keys[512];
  __shared__ unsigned int sh_cutbits;
  __shared__ int sh_m;

  for (int j = tid; j < 256; j += NTHR) hist[j] = 0;
  if (tid == 0) sh_m = 0;
  __syncthreads();

  // ---- pass 1: histogram ----
  if (use_t) {
    const float4* src4 = (const float4*)(ts + (size_t)bc * NANCH + (size_t)p * PARTN);
    for (int i = tid; i < PARTN4; i += NTHR) {
      float4 v = src4[i];
      hist_add(v.x, hist); hist_add(v.y, hist);
      hist_add(v.z, hist); hist_add(v.w, hist);
    }
  } else {
    const float* src = scores + ((size_t)b * NANCH + (size_t)p * PARTN) * NCLS + c;
    for (int i = tid; i < PARTN; i += NTHR) hist_add(src[(size_t)i * NCLS], hist);
  }
  __syncthreads();

  // ---- wave-parallel cutoff: smallest bin with >=200 items at/above it ----
  if (tid < 64) {
    int base = 255 - 4 * tid;
    int s4 = (int)(hist[base] + hist[base - 1] + hist[base - 2] + hist[base - 3]);
    int cum = s4;
    for (int d = 1; d < 64; d <<= 1) {
      int o = __shfl_up(cum, d, 64);
      if (tid >= d) cum += o;
    }
    unsigned long long bal = __ballot(cum >= TOPK);
    if (bal == 0ull) {
      if (tid == 0) sh_cutbits = 0x3F000000u;  // take every candidate
    } else {
      int l0 = __builtin_ctzll(bal);
      if (tid == l0) {
        unsigned int acc = (unsigned int)(cum - s4);  // count in bins above group
        int cutbin = base - 3;
        for (int k = 0; k < 4; ++k) {
          acc += hist[base - k];
          if (acc >= TOPK) { cutbin = base - k; break; }
        }
        sh_cutbits = 0x3F000000u + ((unsigned int)cutbin << 15);
      }
    }
  }
  __syncthreads();
  const unsigned int cutbits = sh_cutbits;

  // ---- pass 2: compact candidate keys ----
  const int gbase = p * PARTN;
  if (use_t) {
    const float4* src4 = (const float4*)(ts + (size_t)bc * NANCH + (size_t)p * PARTN);
    for (int i = tid; i < PARTN4; i += NTHR) {
      float4 v = src4[i];
      int gi = gbase + 4 * i;
      compact_add(v.x, gi,     cutbits, keys, &sh_m);
      compact_add(v.y, gi + 1, cutbits, keys, &sh_m);
      compact_add(v.z, gi + 2, cutbits, keys, &sh_m);
      compact_add(v.w, gi + 3, cutbits, keys, &sh_m);
    }
  } else {
    const float* src = scores + ((size_t)b * NANCH + (size_t)p * PARTN) * NCLS + c;
    for (int i = tid; i < PARTN; i += NTHR)
      compact_add(src[(size_t)i * NCLS], gbase + i, cutbits, keys, &sh_m);
  }
  __syncthreads();

  int M = sh_m; if (M > 512) M = 512;
  const int S = (M <= 256) ? 256 : 512;
  for (int j = M + tid; j < S; j += NTHR) keys[j] = 0ull;

  // ---- bitonic sort S elements, descending ----
  for (int size = 2; size <= S; size <<= 1) {
    for (int st = size >> 1; st > 0; st >>= 1) {
      __syncthreads();
      for (int t = tid; t < (S >> 1); t += NTHR) {
        int lo = 2 * t - (t & (st - 1));
        int hi = lo + st;
        bool desc = ((lo & size) == 0);
        unsigned long long a = keys[lo], bb = keys[hi];
        if ((a < bb) == desc) { keys[lo] = bb; keys[hi] = a; }
      }
    }
  }
  __syncthreads();

  if (tid < TOPK) topkeys[(size_t)blk * TOPK + tid] = keys[tid];
}

// ---------------------------------------------------------------------------
// K3 (stage 2): merge 4 sorted part-lists -> exact top-200, NMS, emit
// ---------------------------------------------------------------------------
__global__ __launch_bounds__(NTHR) void stage2_k(
    const float* __restrict__ boxes, const unsigned long long* __restrict__ topkeys,
    float* __restrict__ out) {
  const int bc = blockIdx.x;
  const int b = bc / NCLS;
  const int c = bc - b * NCLS;
  const int tid = threadIdx.x;

  __shared__ unsigned long long keys[1024];
  __shared__ float sx1[TOPK], sy1[TOPK], sx2[TOPK], sy2[TOPK], sar[TOPK], ssc[TOPK];
  __shared__ int skeep[TOPK];

  for (int j = tid; j < 1024; j += NTHR) keys[j] = 0ull;
  __syncthreads();

  // load: even parts descending at p*256+j; odd parts reversed (ascending,
  // zeros first) at p*256 + 255 - j  ->  each 512-half is bitonic
  const unsigned long long* tk = topkeys + (size_t)bc * (NPART * TOPK);
  for (int f = tid; f < NPART * TOPK; f += NTHR) {
    int p = f / TOPK, j = f - p * TOPK;
    unsigned long long k = tk[f];
    int slot = (p & 1) ? (p * 256 + 255 - j) : (p * 256 + j);
    keys[slot] = k;
  }
  __syncthreads();

  // merge A: each 512-half -> sorted descending (pairs never cross halves)
  for (int st = 256; st > 0; st >>= 1) {
    for (int t = tid; t < 512; t += NTHR) {
      int lo = 2 * t - (t & (st - 1));
      int hi = lo + st;
      unsigned long long a = keys[lo], bb = keys[hi];
      if (a < bb) { keys[lo] = bb; keys[hi] = a; }
    }
    __syncthreads();
  }
  // reverse upper half -> ascending; whole 1024 becomes bitonic
  for (int t = tid; t < 256; t += NTHR) {
    unsigned long long a = keys[512 + t], bb = keys[1023 - t];
    keys[512 + t] = bb; keys[1023 - t] = a;
  }
  __syncthreads();
  // merge B: 1024 -> sorted descending
  for (int st = 512; st > 0; st >>= 1) {
    for (int t = tid; t < 512; t += NTHR) {
      int lo = 2 * t - (t & (st - 1));
      int hi = lo + st;
      unsigned long long a = keys[lo], bb = keys[hi];
      if (a < bb) { keys[lo] = bb; keys[hi] = a; }
    }
    __syncthreads();
  }

  // ---- gather top-200 boxes ----
  if (tid < TOPK) {
    unsigned long long key = keys[tid];
    int valid = (key != 0ull);
    float sc = __uint_as_float((unsigned int)(key >> 32));
    unsigned int idx = 0xFFFFFFFFu - (unsigned int)(key & 0xFFFFFFFFull);
    float4 bx = make_float4(0.f, 0.f, 0.f, 0.f);
    if (valid) bx = ((const float4*)boxes)[(size_t)b * NANCH + idx];
    sx1[tid] = bx.x; sy1[tid] = bx.y; sx2[tid] = bx.z; sy2[tid] = bx.w;
    sar[tid] = __fmul_rn(bx.z - bx.x, bx.w - bx.y);   // _rn: block FMA contraction
    ssc[tid] = valid ? sc : 0.f;
    skeep[tid] = valid;
  }
  __syncthreads();

  // ---- sequential NMS, single wave, register-resident (no barriers) ------
  if (tid < 64) {
    const int lane = tid;
    float x1v[4], y1v[4], x2v[4], y2v[4], av[4];
    int km = 0;  // keep bits for slots j = lane + 64*r
#pragma unroll
    for (int r = 0; r < 4; ++r) {
      int j = lane + (r << 6);
      if (j < TOPK) {
        x1v[r] = sx1[j]; y1v[r] = sy1[j]; x2v[r] = sx2[j]; y2v[r] = sy2[j];
        av[r] = sar[j];
        if (skeep[j]) km |= (1 << r);
      } else {
        x1v[r] = 0.f; y1v[r] = 0.f; x2v[r] = 0.f; y2v[r] = 0.f; av[r] = 0.f;
      }
    }
#pragma unroll
    for (int ri = 0; ri < 4; ++ri) {          // static ri -> register indices
      const int imax = (ri == 3) ? (TOPK - 192) : 64;
      for (int li = 0; li < imax; ++li) {
        const int i = (ri << 6) + li;
        int kmi = __shfl(km, li, 64);         // current keep[i] (wave-uniform)
        if (!((kmi >> ri) & 1)) continue;
        float xi1 = __shfl(x1v[ri], li, 64);
        float yi1 = __shfl(y1v[ri], li, 64);
        float xi2 = __shfl(x2v[ri], li, 64);
        float yi2 = __shfl(y2v[ri], li, 64);
        float ai  = __shfl(av[ri],  li, 64);
#pragma unroll
        for (int r = 0; r < 4; ++r) {
          int j = lane + (r << 6);
          if (j > i && j < TOPK && ((km >> r) & 1)) {
            float xx1 = fmaxf(xi1, x1v[r]);
            float yy1 = fmaxf(yi1, y1v[r]);
            float xx2 = fminf(xi2, x2v[r]);
            float yy2 = fminf(yi2, y2v[r]);
            float iw = fmaxf(0.f, __fsub_rn(xx2, xx1));
            float ih = fmaxf(0.f, __fsub_rn(yy2, yy1));
            float inter = __fmul_rn(iw, ih);
            float denom = __fsub_rn(__fadd_rn(ai, av[r]), inter);
            float iou = __fdiv_rn(inter, denom);   // IEEE div: matches XLA bitwise
            if (iou > 0.5f) km &= ~(1 << r);
          }
        }
      }
    }
#pragma unroll
    for (int r = 0; r < 4; ++r) {
      int j = lane + (r << 6);
      if (j < TOPK) skeep[j] = (km >> r) & 1;
    }
  }
  __syncthreads();

  // ---- emit (box4, score, class) rows, zeroed where not kept -------------
  const size_t base = ((size_t)b * NCLS + c) * (TOPK * 6);
  for (int f = tid; f < TOPK * 6; f += NTHR) {
    int k = f / 6, comp = f - k * 6;
    float v = 0.f;
    if (skeep[k]) {
      switch (comp) {
        case 0: v = sx1[k]; break;
        case 1: v = sy1[k]; break;
        case 2: v = sx2[k]; break;
        case 3: v = sy2[k]; break;
        case 4: v = ssc[k]; break;
        default: v = (float)c; break;
      }
    }
    out[base + f] = v;
  }
}

// ---------------------------------------------------------------------------
// Fallback: proven monolithic kernel (strided reads), used only if ws tiny
// ---------------------------------------------------------------------------
__global__ __launch_bounds__(NTHR) void select_nms_k(
    const float* __restrict__ boxes, const float* __restrict__ scores,
    float* __restrict__ out) {
  const int blk = blockIdx.x;
  const int b = blk / NCLS;
  const int c = blk - b * NCLS;
  const int tid = threadIdx.x;

  __shared__ unsigned int hist[256];
  __shared__ unsigned long long keys[1024];
  __shared__ float sx1[TOPK], sy1[TOPK], sx2[TOPK], sy2[TOPK], sar[TOPK], ssc[TOPK];
  __shared__ int skeep[TOPK];
  __shared__ unsigned int sh_cutbits;
  __shared__ int sh_m;

  const float* src = scores + (size_t)b * NANCH * NCLS + c;

  for (int j = tid; j < 256; j += NTHR) hist[j] = 0;
  if (tid == 0) sh_m = 0;
  __syncthreads();

  for (int i = tid; i < NANCH; i += NTHR) hist_add(src[(size_t)i * NCLS], hist);
  __syncthreads();

  if (tid == 0) {
    unsigned int acc = 0;
    int cut = 0;
    for (int bin = 255; bin >= 0; --bin) {
      acc += hist[bin];
      if (acc >= TOPK) { cut = bin; break; }
    }
    sh_cutbits = 0x3F000000u + ((unsigned int)cut << 15);
  }
  __syncthreads();
  const unsigned int cutbits = sh_cutbits;

  for (int i = tid; i < NANCH; i += NTHR) {
    float s = src[(size_t)i * NCLS];
    if (s > 0.5f && __float_as_uint(s) >= cutbits) {
      int slot = atomicAdd(&sh_m, 1);
      if (slot < 1024)
        keys[slot] = ((unsigned long long)__float_as_uint(s) << 32) |
                     (unsigned long long)(0xFFFFFFFFu - (unsigned int)i);
    }
  }
  __syncthreads();
  int M = sh_m; if (M > 1024) M = 1024;
  for (int j = M + tid; j < 1024; j += NTHR) keys[j] = 0ull;

  for (int size = 2; size <= 1024; size <<= 1) {
    for (int st = size >> 1; st > 0; st >>= 1) {
      __syncthreads();
      for (int t = tid; t < 512; t += NTHR) {
        int lo = 2 * t - (t & (st - 1));
        int hi = lo + st;
        bool desc = ((lo & size) == 0);
        unsigned long long a = keys[lo], bb = keys[hi];
        if ((a < bb) == desc) { keys[lo] = bb; keys[hi] = a; }
      }
    }
  }
  __syncthreads();

  if (tid < TOPK) {
    unsigned long long key = keys[tid];
    int valid = (key != 0ull);
    float sc = __uint_as_float((unsigned int)(key >> 32));
    unsigned int idx = 0xFFFFFFFFu - (unsigned int)(key & 0xFFFFFFFFull);
    float4 bx = make_float4(0.f, 0.f, 0.f, 0.f);
    if (valid) bx = ((const float4*)boxes)[(size_t)b * NANCH + idx];
    sx1[tid] = bx.x; sy1[tid] = bx.y; sx2[tid] = bx.z; sy2[tid] = bx.w;
    sar[tid] = __fmul_rn(bx.z - bx.x, bx.w - bx.y);
    ssc[tid] = valid ? sc : 0.f;
    skeep[tid] = valid;
  }
  __syncthreads();

  if (tid < 64) {
    const int lane = tid;
    float x1v[4], y1v[4], x2v[4], y2v[4], av[4];
    int km = 0;
#pragma unroll
    for (int r = 0; r < 4; ++r) {
      int j = lane + (r << 6);
      if (j < TOPK) {
        x1v[r] = sx1[j]; y1v[r] = sy1[j]; x2v[r] = sx2[j]; y2v[r] = sy2[j];
        av[r] = sar[j];
        if (skeep[j]) km |= (1 << r);
      } else {
        x1v[r] = 0.f; y1v[r] = 0.f; x2v[r] = 0.f; y2v[r] = 0.f; av[r] = 0.f;
      }
    }
#pragma unroll
    for (int ri = 0; ri < 4; ++ri) {
      const int imax = (ri == 3) ? (TOPK - 192) : 64;
      for (int li = 0; li < imax; ++li) {
        const int i = (ri << 6) + li;
        int kmi = __shfl(km, li, 64);
        if (!((kmi >> ri) & 1)) continue;
        float xi1 = __shfl(x1v[ri], li, 64);
        float yi1 = __shfl(y1v[ri], li, 64);
        float xi2 = __shfl(x2v[ri], li, 64);
        float yi2 = __shfl(y2v[ri], li, 64);
        float ai  = __shfl(av[ri],  li, 64);
#pragma unroll
        for (int r = 0; r < 4; ++r) {
          int j = lane + (r << 6);
          if (j > i && j < TOPK && ((km >> r) & 1)) {
            float xx1 = fmaxf(xi1, x1v[r]);
            float yy1 = fmaxf(yi1, y1v[r]);
            float xx2 = fminf(xi2, x2v[r]);
            float yy2 = fminf(yi2, y2v[r]);
            float iw = fmaxf(0.f, __fsub_rn(xx2, xx1));
            float ih = fmaxf(0.f, __fsub_rn(yy2, yy1));
            float inter = __fmul_rn(iw, ih);
            float denom = __fsub_rn(__fadd_rn(ai, av[r]), inter);
            float iou = __fdiv_rn(inter, denom);
            if (iou > 0.5f) km &= ~(1 << r);
          }
        }
      }
    }
#pragma unroll
    for (int r = 0; r < 4; ++r) {
      int j = lane + (r << 6);
      if (j < TOPK) skeep[j] = (km >> r) & 1;
    }
  }
  __syncthreads();

  const size_t base = ((size_t)b * NCLS + c) * (TOPK * 6);
  for (int f = tid; f < TOPK * 6; f += NTHR) {
    int k = f / 6, comp = f - k * 6;
    float v = 0.f;
    if (skeep[k]) {
      switch (comp) {
        case 0: v = sx1[k]; break;
        case 1: v = sy1[k]; break;
        case 2: v = sx2[k]; break;
        case 3: v = sy2[k]; break;
        case 4: v = ssc[k]; break;
        default: v = (float)c; break;
      }
    }
    out[base + f] = v;
  }
}

// ---------------------------------------------------------------------------
extern "C" void kernel_launch(void* const* d_in, const int* in_sizes, int n_in,
                              void* d_out, int out_size, void* d_ws, size_t ws_size,
                              hipStream_t stream) {
  (void)in_sizes; (void)n_in; (void)out_size;
  const float* boxes  = (const float*)d_in[0];
  const float* scores = (const float*)d_in[1];
  float* out = (float*)d_out;

  const size_t need_ts = (size_t)B_IMG * NCLS * NANCH * sizeof(float);             // 44.4 MB
  const size_t need_tk = (size_t)B_IMG * NCLS * NPART * TOPK * sizeof(uint64_t);   // 4.1 MB

  if (ws_size >= need_ts + need_tk) {
    float* ts = (float*)d_ws;
    unsigned long long* topkeys = (unsigned long long*)((char*)d_ws + need_ts);
    dim3 tgrid((NANCH + 63) / 64, B_IMG);
    transpose_scores_k<<<tgrid, NTHR, 0, stream>>>(scores, ts);
    stage1_k<<<B_IMG * NCLS * NPART, NTHR, 0, stream>>>(scores, ts, 1, topkeys);
    stage2_k<<<B_IMG * NCLS, NTHR, 0, stream>>>(boxes, topkeys, out);
  } else if (ws_size >= need_tk) {
    unsigned long long* topkeys = (unsigned long long*)d_ws;
    stage1_k<<<B_IMG * NCLS * NPART, NTHR, 0, stream>>>(scores, (const float*)0, 0, topkeys);
    stage2_k<<<B_IMG * NCLS, NTHR, 0, stream>>>(boxes, topkeys, out);
  } else {
    select_nms_k<<<B_IMG * NCLS, NTHR, 0, stream>>>(boxes, scores, out);
  }
}

// Round 3
// 113.460 us; speedup vs baseline: 1.4187x; 1.1412x over previous
//
#include <hip/hip_runtime.h>
#include <stdint.h>

#define B_IMG  8
#define NANCH  17328          // A*HW = 3*5776
#define NCLS   80
#define TOPK   200
#define NPART  4
#define PARTN  (NANCH / NPART)    // 4332
#define PARTN4 (PARTN / 4)        // 1083 float4s
#define NTHR   256

// ---------------------------------------------------------------------------
// K1: transpose scores [B][N][C] -> [B][C][N] so per-class reads are coalesced
// ---------------------------------------------------------------------------
__global__ __launch_bounds__(NTHR) void transpose_scores_k(
    const float* __restrict__ scores, float* __restrict__ ts) {
  __shared__ float tile[64][81];  // +1 pad: conflict-free transposed reads
  const int b = blockIdx.y;
  const int n0 = blockIdx.x * 64;
  const int tid = threadIdx.x;

  for (int f = tid; f < 64 * NCLS; f += NTHR) {
    int dn = f / NCLS, c = f - dn * NCLS;
    int n = n0 + dn;
    if (n < NANCH) tile[dn][c] = scores[((size_t)b * NANCH + n) * NCLS + c];
  }
  __syncthreads();
  for (int f = tid; f < NCLS * 64; f += NTHR) {
    int c = f >> 6, dn = f & 63;
    int n = n0 + dn;
    if (n < NANCH) ts[((size_t)b * NCLS + c) * NANCH + n] = tile[dn][c];
  }
}

// ---------------------------------------------------------------------------
// helpers
// ---------------------------------------------------------------------------
__device__ __forceinline__ void hist_add(float s, unsigned int* hist) {
  if (s > 0.5f) {
    unsigned int bin = (__float_as_uint(s) - 0x3F000000u) >> 15;
    if (bin > 255u) bin = 255u;
    atomicAdd(&hist[bin], 1u);
  }
}

__device__ __forceinline__ void compact_add(float s, int gidx, unsigned int cutbits,
                                            unsigned long long* keys, int* sh_m) {
  if (s > 0.5f && __float_as_uint(s) >= cutbits) {
    int slot = atomicAdd(sh_m, 1);
    if (slot < 512)
      keys[slot] = ((unsigned long long)__float_as_uint(s) << 32) |
                   (unsigned long long)(0xFFFFFFFFu - (unsigned int)gidx);
  }
}

// ---------------------------------------------------------------------------
// K2 (stage 1): per-(b,c,part) exact top-200 keys -> global ws
// blk = (b*NCLS + c)*NPART + p
// ---------------------------------------------------------------------------
__global__ __launch_bounds__(NTHR) void stage1_k(
    const float* __restrict__ scores, const float* __restrict__ ts, int use_t,
    unsigned long long* __restrict__ topkeys) {
  const int blk = blockIdx.x;
  const int p = blk & (NPART - 1);
  const int bc = blk >> 2;
  const int b = bc / NCLS;
  const int c = bc - b * NCLS;
  const int tid = threadIdx.x;

  __shared__ unsigned int hist[256];
  __shared__ unsigned long long keys[512];
  __shared__ unsigned int sh_cutbits;
  __shared__ int sh_m;

  for (int j = tid; j < 256; j += NTHR) hist[j] = 0;
  if (tid == 0) sh_m = 0;
  __syncthreads();

  // ---- pass 1: histogram ----
  if (use_t) {
    const float4* src4 = (const float4*)(ts + (size_t)bc * NANCH + (size_t)p * PARTN);
    for (int i = tid; i < PARTN4; i += NTHR) {
      float4 v = src4[i];
      hist_add(v.x, hist); hist_add(v.y, hist);
      hist_add(v.z, hist); hist_add(v.w, hist);
    }
  } else {
    const float* src = scores + ((size_t)b * NANCH + (size_t)p * PARTN) * NCLS + c;
    for (int i = tid; i < PARTN; i += NTHR) hist_add(src[(size_t)i * NCLS], hist);
  }
  __syncthreads();

  // ---- wave-parallel cutoff: smallest bin with >=200 items at/above it ----
  if (tid < 64) {
    int base = 255 - 4 * tid;
    int s4 = (int)(hist[base] + hist[base - 1] + hist[base - 2] + hist[base - 3]);
    int cum = s4;
    for (int d = 1; d < 64; d <<= 1) {
      int o = __shfl_up(cum, d, 64);
      if (tid >= d) cum += o;
    }
    unsigned long long bal = __ballot(cum >= TOPK);
    if (bal == 0ull) {
      if (tid == 0) sh_cutbits = 0x3F000000u;  // take every candidate
    } else {
      int l0 = __builtin_ctzll(bal);
      if (tid == l0) {
        unsigned int acc = (unsigned int)(cum - s4);  // count in bins above group
        int cutbin = base - 3;
        for (int k = 0; k < 4; ++k) {
          acc += hist[base - k];
          if (acc >= TOPK) { cutbin = base - k; break; }
        }
        sh_cutbits = 0x3F000000u + ((unsigned int)cutbin << 15);
      }
    }
  }
  __syncthreads();
  const unsigned int cutbits = sh_cutbits;

  // ---- pass 2: compact candidate keys ----
  const int gbase = p * PARTN;
  if (use_t) {
    const float4* src4 = (const float4*)(ts + (size_t)bc * NANCH + (size_t)p * PARTN);
    for (int i = tid; i < PARTN4; i += NTHR) {
      float4 v = src4[i];
      int gi = gbase + 4 * i;
      compact_add(v.x, gi,     cutbits, keys, &sh_m);
      compact_add(v.y, gi + 1, cutbits, keys, &sh_m);
      compact_add(v.z, gi + 2, cutbits, keys, &sh_m);
      compact_add(v.w, gi + 3, cutbits, keys, &sh_m);
    }
  } else {
    const float* src = scores + ((size_t)b * NANCH + (size_t)p * PARTN) * NCLS + c;
    for (int i = tid; i < PARTN; i += NTHR)
      compact_add(src[(size_t)i * NCLS], gbase + i, cutbits, keys, &sh_m);
  }
  __syncthreads();

  int M = sh_m; if (M > 512) M = 512;
  const int S = (M <= 256) ? 256 : 512;
  for (int j = M + tid; j < S; j += NTHR) keys[j] = 0ull;

  // ---- bitonic sort S elements, descending ----
  for (int size = 2; size <= S; size <<= 1) {
    for (int st = size >> 1; st > 0; st >>= 1) {
      __syncthreads();
      for (int t = tid; t < (S >> 1); t += NTHR) {
        int lo = 2 * t - (t & (st - 1));
        int hi = lo + st;
        bool desc = ((lo & size) == 0);
        unsigned long long a = keys[lo], bb = keys[hi];
        if ((a < bb) == desc) { keys[lo] = bb; keys[hi] = a; }
      }
    }
  }
  __syncthreads();

  if (tid < TOPK) topkeys[(size_t)blk * TOPK + tid] = keys[tid];
}

// ---------------------------------------------------------------------------
// K3 (stage 2): merge 4 sorted part-lists -> exact top-200, bitmask NMS, emit
// ---------------------------------------------------------------------------
__global__ __launch_bounds__(NTHR) void stage2_k(
    const float* __restrict__ boxes, const unsigned long long* __restrict__ topkeys,
    float* __restrict__ out) {
  const int bc = blockIdx.x;
  const int b = bc / NCLS;
  const int c = bc - b * NCLS;
  const int tid = threadIdx.x;

  __shared__ unsigned long long keys[1024];
  __shared__ float sx1[256], sy1[256], sx2[256], sy2[256], sar[256], ssc[256];
  __shared__ int skeep[256];
  __shared__ unsigned long long sup[TOPK][4];   // suppression matrix, 6.4 KB

  for (int j = tid; j < 1024; j += NTHR) keys[j] = 0ull;
  __syncthreads();

  // load: even parts descending at p*256+j; odd parts reversed (ascending,
  // zeros first) at p*256 + 255 - j  ->  each 512-half is bitonic
  const unsigned long long* tk = topkeys + (size_t)bc * (NPART * TOPK);
  for (int f = tid; f < NPART * TOPK; f += NTHR) {
    int p = f / TOPK, j = f - p * TOPK;
    unsigned long long k = tk[f];
    int slot = (p & 1) ? (p * 256 + 255 - j) : (p * 256 + j);
    keys[slot] = k;
  }
  __syncthreads();

  // merge A: each 512-half -> sorted descending (pairs never cross halves)
  for (int st = 256; st > 0; st >>= 1) {
    for (int t = tid; t < 512; t += NTHR) {
      int lo = 2 * t - (t & (st - 1));
      int hi = lo + st;
      unsigned long long a = keys[lo], bb = keys[hi];
      if (a < bb) { keys[lo] = bb; keys[hi] = a; }
    }
    __syncthreads();
  }
  // reverse upper half -> ascending; whole 1024 becomes bitonic
  for (int t = tid; t < 256; t += NTHR) {
    unsigned long long a = keys[512 + t], bb = keys[1023 - t];
    keys[512 + t] = bb; keys[1023 - t] = a;
  }
  __syncthreads();
  // merge B: 1024 -> sorted descending
  for (int st = 512; st > 0; st >>= 1) {
    for (int t = tid; t < 512; t += NTHR) {
      int lo = 2 * t - (t & (st - 1));
      int hi = lo + st;
      unsigned long long a = keys[lo], bb = keys[hi];
      if (a < bb) { keys[lo] = bb; keys[hi] = a; }
    }
    __syncthreads();
  }

  // ---- gather top-200 boxes (slots 200..255 zero-filled) ------------------
  {
    unsigned long long key = keys[tid];
    int valid = (tid < TOPK) && (key != 0ull);
    float sc = __uint_as_float((unsigned int)(key >> 32));
    unsigned int idx = 0xFFFFFFFFu - (unsigned int)(key & 0xFFFFFFFFull);
    float4 bx = make_float4(0.f, 0.f, 0.f, 0.f);
    if (valid) bx = ((const float4*)boxes)[(size_t)b * NANCH + idx];
    sx1[tid] = bx.x; sy1[tid] = bx.y; sx2[tid] = bx.z; sy2[tid] = bx.w;
    sar[tid] = __fmul_rn(bx.z - bx.x, bx.w - bx.y);   // _rn: block FMA contraction
    ssc[tid] = valid ? sc : 0.f;
    skeep[tid] = valid;
  }
  __syncthreads();

  // ---- parallel suppression-matrix build (upper triangle) -----------------
  {
    const int wv = tid >> 6, lane = tid & 63;
    // per-lane j-candidate boxes, hoisted out of the row loop
    float jx1[4], jy1[4], jx2[4], jy2[4], ja[4];
#pragma unroll
    for (int r = 0; r < 4; ++r) {
      int j = (r << 6) | lane;
      jx1[r] = sx1[j]; jy1[r] = sy1[j]; jx2[r] = sx2[j]; jy2[r] = sy2[j];
      ja[r] = sar[j];
    }
    for (int i = wv; i < TOPK; i += 4) {
      const float xi1 = sx1[i], yi1 = sy1[i], xi2 = sx2[i], yi2 = sy2[i];
      const float ai = sar[i];
#pragma unroll
      for (int r = 0; r < 4; ++r) {
        unsigned long long word = 0ull;
        if ((r << 6) + 63 > i) {            // wave-uniform: block has some j > i
          const int j = (r << 6) | lane;
          bool s = false;
          if (j > i && j < TOPK) {
            float xx1 = fmaxf(xi1, jx1[r]);
            float yy1 = fmaxf(yi1, jy1[r]);
            float xx2 = fminf(xi2, jx2[r]);
            float yy2 = fminf(yi2, jy2[r]);
            float iw = fmaxf(0.f, __fsub_rn(xx2, xx1));
            float ih = fmaxf(0.f, __fsub_rn(yy2, yy1));
            float inter = __fmul_rn(iw, ih);
            float denom = __fsub_rn(__fadd_rn(ai, ja[r]), inter);
            // fast approx decision; exact IEEE div only inside the guard band
            float q = __fmul_rn(inter, __builtin_amdgcn_rcpf(denom));
            s = q > 0.5f;
            if (fabsf(q - 0.5f) < 1e-5f)
              s = __fdiv_rn(inter, denom) > 0.5f;   // bitwise-matches XLA
          }
          word = __ballot(s);
        }
        if (lane == 0) sup[i][r] = word;
      }
    }
  }
  __syncthreads();

  // ---- serial scan: pure bit-ops, keep state in 4 u64 regs (wave 0) -------
  if (tid < 64) {
    unsigned long long k0 = __ballot(skeep[tid] != 0);
    unsigned long long k1 = __ballot(skeep[64 + tid] != 0);
    unsigned long long k2 = __ballot(skeep[128 + tid] != 0);
    unsigned long long k3 = __ballot(skeep[192 + tid] != 0);  // 200..255 are 0
#define NMS_SCAN_WORD(KW, BASE, CNT)                                     \
    _Pragma("unroll 8")                                                  \
    for (int li = 0; li < (CNT); ++li) {                                 \
      unsigned long long s0 = sup[(BASE) + li][0];                       \
      unsigned long long s1 = sup[(BASE) + li][1];                       \
      unsigned long long s2 = sup[(BASE) + li][2];                       \
      unsigned long long s3 = sup[(BASE) + li][3];                       \
      unsigned long long m = 0ull - ((KW >> li) & 1ull);                 \
      k0 &= ~(s0 & m); k1 &= ~(s1 & m);                                  \
      k2 &= ~(s2 & m); k3 &= ~(s3 & m);                                  \
    }
    NMS_SCAN_WORD(k0, 0, 64)
    NMS_SCAN_WORD(k1, 64, 64)
    NMS_SCAN_WORD(k2, 128, 64)
    NMS_SCAN_WORD(k3, 192, 8)
#undef NMS_SCAN_WORD
    skeep[tid]        = (int)((k0 >> tid) & 1ull);
    skeep[64 + tid]   = (int)((k1 >> tid) & 1ull);
    skeep[128 + tid]  = (int)((k2 >> tid) & 1ull);
    skeep[192 + tid]  = (int)((k3 >> tid) & 1ull);
  }
  __syncthreads();

  // ---- emit (box4, score, class) rows, zeroed where not kept -------------
  const size_t base = ((size_t)b * NCLS + c) * (TOPK * 6);
  for (int f = tid; f < TOPK * 6; f += NTHR) {
    int k = f / 6, comp = f - k * 6;
    float v = 0.f;
    if (skeep[k]) {
      switch (comp) {
        case 0: v = sx1[k]; break;
        case 1: v = sy1[k]; break;
        case 2: v = sx2[k]; break;
        case 3: v = sy2[k]; break;
        case 4: v = ssc[k]; break;
        default: v = (float)c; break;
      }
    }
    out[base + f] = v;
  }
}

// ---------------------------------------------------------------------------
// Fallback: proven monolithic kernel (strided reads), used only if ws tiny
// ---------------------------------------------------------------------------
__global__ __launch_bounds__(NTHR) void select_nms_k(
    const float* __restrict__ boxes, const float* __restrict__ scores,
    float* __restrict__ out) {
  const int blk = blockIdx.x;
  const int b = blk / NCLS;
  const int c = blk - b * NCLS;
  const int tid = threadIdx.x;

  __shared__ unsigned int hist[256];
  __shared__ unsigned long long keys[1024];
  __shared__ float sx1[TOPK], sy1[TOPK], sx2[TOPK], sy2[TOPK], sar[TOPK], ssc[TOPK];
  __shared__ int skeep[TOPK];
  __shared__ unsigned int sh_cutbits;
  __shared__ int sh_m;

  const float* src = scores + (size_t)b * NANCH * NCLS + c;

  for (int j = tid; j < 256; j += NTHR) hist[j] = 0;
  if (tid == 0) sh_m = 0;
  __syncthreads();

  for (int i = tid; i < NANCH; i += NTHR) hist_add(src[(size_t)i * NCLS], hist);
  __syncthreads();

  if (tid == 0) {
    unsigned int acc = 0;
    int cut = 0;
    for (int bin = 255; bin >= 0; --bin) {
      acc += hist[bin];
      if (acc >= TOPK) { cut = bin; break; }
    }
    sh_cutbits = 0x3F000000u + ((unsigned int)cut << 15);
  }
  __syncthreads();
  const unsigned int cutbits = sh_cutbits;

  for (int i = tid; i < NANCH; i += NTHR) {
    float s = src[(size_t)i * NCLS];
    if (s > 0.5f && __float_as_uint(s) >= cutbits) {
      int slot = atomicAdd(&sh_m, 1);
      if (slot < 1024)
        keys[slot] = ((unsigned long long)__float_as_uint(s) << 32) |
                     (unsigned long long)(0xFFFFFFFFu - (unsigned int)i);
    }
  }
  __syncthreads();
  int M = sh_m; if (M > 1024) M = 1024;
  for (int j = M + tid; j < 1024; j += NTHR) keys[j] = 0ull;

  for (int size = 2; size <= 1024; size <<= 1) {
    for (int st = size >> 1; st > 0; st >>= 1) {
      __syncthreads();
      for (int t = tid; t < 512; t += NTHR) {
        int lo = 2 * t - (t & (st - 1));
        int hi = lo + st;
        bool desc = ((lo & size) == 0);
        unsigned long long a = keys[lo], bb = keys[hi];
        if ((a < bb) == desc) { keys[lo] = bb; keys[hi] = a; }
      }
    }
  }
  __syncthreads();

  if (tid < TOPK) {
    unsigned long long key = keys[tid];
    int valid = (key != 0ull);
    float sc = __uint_as_float((unsigned int)(key >> 32));
    unsigned int idx = 0xFFFFFFFFu - (unsigned int)(key & 0xFFFFFFFFull);
    float4 bx = make_float4(0.f, 0.f, 0.f, 0.f);
    if (valid) bx = ((const float4*)boxes)[(size_t)b * NANCH + idx];
    sx1[tid] = bx.x; sy1[tid] = bx.y; sx2[tid] = bx.z; sy2[tid] = bx.w;
    sar[tid] = __fmul_rn(bx.z - bx.x, bx.w - bx.y);
    ssc[tid] = valid ? sc : 0.f;
    skeep[tid] = valid;
  }
  __syncthreads();

  if (tid < 64) {
    const int lane = tid;
    float x1v[4], y1v[4], x2v[4], y2v[4], av[4];
    int km = 0;
#pragma unroll
    for (int r = 0; r < 4; ++r) {
      int j = lane + (r << 6);
      if (j < TOPK) {
        x1v[r] = sx1[j]; y1v[r] = sy1[j]; x2v[r] = sx2[j]; y2v[r] = sy2[j];
        av[r] = sar[j];
        if (skeep[j]) km |= (1 << r);
      } else {
        x1v[r] = 0.f; y1v[r] = 0.f; x2v[r] = 0.f; y2v[r] = 0.f; av[r] = 0.f;
      }
    }
#pragma unroll
    for (int ri = 0; ri < 4; ++ri) {
      const int imax = (ri == 3) ? (TOPK - 192) : 64;
      for (int li = 0; li < imax; ++li) {
        const int i = (ri << 6) + li;
        int kmi = __shfl(km, li, 64);
        if (!((kmi >> ri) & 1)) continue;
        float xi1 = __shfl(x1v[ri], li, 64);
        float yi1 = __shfl(y1v[ri], li, 64);
        float xi2 = __shfl(x2v[ri], li, 64);
        float yi2 = __shfl(y2v[ri], li, 64);
        float ai  = __shfl(av[ri],  li, 64);
#pragma unroll
        for (int r = 0; r < 4; ++r) {
          int j = lane + (r << 6);
          if (j > i && j < TOPK && ((km >> r) & 1)) {
            float xx1 = fmaxf(xi1, x1v[r]);
            float yy1 = fmaxf(yi1, y1v[r]);
            float xx2 = fminf(xi2, x2v[r]);
            float yy2 = fminf(yi2, y2v[r]);
            float iw = fmaxf(0.f, __fsub_rn(xx2, xx1));
            float ih = fmaxf(0.f, __fsub_rn(yy2, yy1));
            float inter = __fmul_rn(iw, ih);
            float denom = __fsub_rn(__fadd_rn(ai, av[r]), inter);
            float iou = __fdiv_rn(inter, denom);
            if (iou > 0.5f) km &= ~(1 << r);
          }
        }
      }
    }
#pragma unroll
    for (int r = 0; r < 4; ++r) {
      int j = lane + (r << 6);
      if (j < TOPK) skeep[j] = (km >> r) & 1;
    }
  }
  __syncthreads();

  const size_t base = ((size_t)b * NCLS + c) * (TOPK * 6);
  for (int f = tid; f < TOPK * 6; f += NTHR) {
    int k = f / 6, comp = f - k * 6;
    float v = 0.f;
    if (skeep[k]) {
      switch (comp) {
        case 0: v = sx1[k]; break;
        case 1: v = sy1[k]; break;
        case 2: v = sx2[k]; break;
        case 3: v = sy2[k]; break;
        case 4: v = ssc[k]; break;
        default: v = (float)c; break;
      }
    }
    out[base + f] = v;
  }
}

// ---------------------------------------------------------------------------
extern "C" void kernel_launch(void* const* d_in, const int* in_sizes, int n_in,
                              void* d_out, int out_size, void* d_ws, size_t ws_size,
                              hipStream_t stream) {
  (void)in_sizes; (void)n_in; (void)out_size;
  const float* boxes  = (const float*)d_in[0];
  const float* scores = (const float*)d_in[1];
  float* out = (float*)d_out;

  const size_t need_ts = (size_t)B_IMG * NCLS * NANCH * sizeof(float);             // 44.4 MB
  const size_t need_tk = (size_t)B_IMG * NCLS * NPART * TOPK * sizeof(uint64_t);   // 4.1 MB

  if (ws_size >= need_ts + need_tk) {
    float* ts = (float*)d_ws;
    unsigned long long* topkeys = (unsigned long long*)((char*)d_ws + need_ts);
    dim3 tgrid((NANCH + 63) / 64, B_IMG);
    transpose_scores_k<<<tgrid, NTHR, 0, stream>>>(scores, ts);
    stage1_k<<<B_IMG * NCLS * NPART, NTHR, 0, stream>>>(scores, ts, 1, topkeys);
    stage2_k<<<B_IMG * NCLS, NTHR, 0, stream>>>(boxes, topkeys, out);
  } else if (ws_size >= need_tk) {
    unsigned long long* topkeys = (unsigned long long*)d_ws;
    stage1_k<<<B_IMG * NCLS * NPART, NTHR, 0, stream>>>(scores, (const float*)0, 0, topkeys);
    stage2_k<<<B_IMG * NCLS, NTHR, 0, stream>>>(boxes, topkeys, out);
  } else {
    select_nms_k<<<B_IMG * NCLS, NTHR, 0, stream>>>(boxes, scores, out);
  }
}